// Round 8
// baseline (601.144 us; speedup 1.0000x reference)
//
#include <hip/hip_runtime.h>
#include <hip/hip_bf16.h>

// Fused Conv3d(3->16,k=3,valid) + conv_b + ReLU + maxpool2x2x2
// + spatial mean(fp32) + /2 + bias + channel-sum  ->  out[32] fp32.
// Inputs are FLOAT32 (harness materializes reference fp16 as f32).
//
// R8: NO im2col transpose. LDS holds x in natural order:
//   rawT[row=w][tap = ci*16 + dl*4 + hl], 48 real taps + 16 zeros, row
//   stride 144 B; 16B-chunks XOR-swizzled by ((row>>2)&7) for bank health.
// MFMA K=32 runs over the full (dl,hl) 4x4 grid; the 3x3 (kd,kh) window for
// pool cell g=(dd,hh) is selected by ZERO-PADDED WEIGHTS (wtab, init kernel):
//   per g: 3 kw x 2 halves (ci{0,1} | ci2+zeros) = 6 MFMAs; 4 g = 24 MFMAs.
// B-frag = one swizzled ds_read_b128 (6 addresses, reused across g).
// D layout (verified): col=lane&15=w, row=q*4+r=channel. 2x2x2 pool closes
// in-register; wave-reduce; one atomicAdd. Only 2 barriers per block.

typedef __attribute__((ext_vector_type(8))) short short8;
typedef __attribute__((ext_vector_type(4))) float floatx4;

__device__ __forceinline__ short f2bf(float f) {
    unsigned u = __builtin_bit_cast(unsigned, f);
    unsigned r = (u + 0x7FFFu + ((u >> 16) & 1u)) >> 16;
    return (short)r;
}

__device__ __forceinline__ unsigned pkbf2(float a, float b) {
    __hip_bfloat162 h = __float22bfloat162_rn(float2{a, b});  // v_cvt_pk_bf16_f32
    unsigned r;
    __builtin_memcpy(&r, &h, 4);
    return r;
}

#define ROWSH 72   // shorts per rawT row (144 B = 36 dwords; 36%32=4 -> clean b128 reads)

// ---- init: zero-padded weight frags wtab[g][kw][half][lane][8] + out=bias sums ----
__global__ void init_kernel(const float* __restrict__ wg,
                            const float* __restrict__ biasg,
                            short* __restrict__ wtab,   // d_ws: 4*3*2*64*8 bf16 = 24,576 B
                            float* __restrict__ out)    // [32]
{
    const int t = threadIdx.x;               // 0..511
    #pragma unroll
    for (int k3 = 0; k3 < 3; ++k3) {
        const int e = t + 512 * k3;          // frag entry 0..1535
        const int lane = e & 63;
        const int half = (e >> 6) & 1;
        const int gkw  = e >> 7;             // 0..11
        const int kw = gkw % 3, g = gkw / 3;
        const int dd = g >> 1, hh = g & 1;
        const int m = lane & 15, q = lane >> 4;
        short8 v;
        #pragma unroll
        for (int j = 0; j < 8; ++j) {
            const int p = half * 32 + q * 8 + j;    // logical tap position 0..63
            short val = 0;
            if (p < 48) {
                const int ci = p >> 4, dl = (p >> 2) & 3, hl = p & 3;
                const int kd = dl - dd, kh = hl - hh;
                if (kd >= 0 && kd < 3 && kh >= 0 && kh < 3)
                    val = f2bf(wg[m * 81 + (ci * 9 + kd * 3 + kh) * 3 + kw]);
            }
            v[j] = val;
        }
        ((short8*)wtab)[e] = v;
    }
    if (t < 32) {
        float s = 0.f;
        #pragma unroll
        for (int cc = 0; cc < 16; ++cc) s += biasg[cc];
        out[t] = s;   // conv blocks atomicAdd on top (overwrites poison)
    }
}

__global__ __launch_bounds__(512, 8) void fused_conv_pool_reduce(
    const float* __restrict__ xg,    // f32 [32][3][32][128][128]
    const short* __restrict__ wtab,  // bf16 frag table in d_ws
    const float* __restrict__ cbg,   // f32 [16]
    float* __restrict__ out)         // f32 [32]
{
    __shared__ __align__(16) short rawT[130 * ROWSH];  // 18,720 B
    __shared__ float wsums[8];

    const int hp  = blockIdx.x;   // 0..62
    const int dp  = blockIdx.y;   // 0..14
    const int b   = blockIdx.z;   // 0..31
    const int tid = threadIdx.x;  // 0..511
    const int lane = tid & 63;
    const int wv   = tid >> 6;

    const int q = lane >> 4;      // K-quad
    const int n = lane & 15;      // w position within tile (N = D col)

    // ---- zero fill: chunks 6,7 (taps 48..63) of rows 0..127, swizzled ----
    {
        const int row = tid >> 2, k = tid & 3;
        const int phys = (6 + (k >> 1)) ^ ((row >> 2) & 7);
        *(unsigned long long*)((char*)rawT + row * 144 + phys * 16 + (k & 1) * 8) = 0ULL;
    }
    // rows 128,129 fully zero (finite garbage rows for masked-out lanes)
    if (tid < 36)
        *(unsigned long long*)((char*)rawT + 128 * 144 + tid * 8) = 0ULL;

    // ---- phase 1: coalesced float4 loads -> swizzled scattered b16 writes ----
    // thread = (w4 0..31, hr 0..3, dr 0..3); writes rows 4w4+i, taps (ci,dr,hr)
    {
        const int w4 = tid & 31, hr = (tid >> 5) & 3, dr = (tid >> 7) & 3;
        const float* src = xg + ((size_t)(b * 3) * 32 + 2 * dp + dr) * 16384
                              + (2 * hp + hr) * 128 + w4 * 4;
        const int swz = (w4 & 7) << 4;               // row>>2 == w4 for rows 4w4+i
        char* base0 = (char*)rawT + (w4 * 4) * 144;
        #pragma unroll
        for (int ci = 0; ci < 3; ++ci) {
            const floatx4 v = *(const floatx4*)(src + (size_t)ci * 524288);
            const int P = ci * 32 + dr * 8 + hr * 2;  // tap byte 0..94 (chunks 0..5)
            char* dst = base0 + (P ^ swz);
            const unsigned p0 = pkbf2(v[0], v[1]);
            const unsigned p1 = pkbf2(v[2], v[3]);
            *(short*)(dst + 0 * 144) = (short)(p0 & 0xFFFF);
            *(short*)(dst + 1 * 144) = (short)(p0 >> 16);
            *(short*)(dst + 2 * 144) = (short)(p1 & 0xFFFF);
            *(short*)(dst + 3 * 144) = (short)(p1 >> 16);
        }
    }
    __syncthreads();

    // ---- B-frag addresses: 6 swizzled b128 pointers, reused across all g ----
    const int w0 = wv * 16;
    const short* baddr[3][2];
    #pragma unroll
    for (int kw = 0; kw < 3; ++kw) {
        const int r = w0 + n + kw;                   // row 0..129
        const int a = (r >> 2) & 7;
        #pragma unroll
        for (int h = 0; h < 2; ++h) {
            const int chunk = (q + 4 * h) ^ a;
            baddr[kw][h] = (const short*)((const char*)rawT + r * 144 + chunk * 16);
        }
    }

    // ---- 24 MFMAs: g=(dd,hh) selects weights; pool over g in-register ----
    floatx4 mx = {-3.0e38f, -3.0e38f, -3.0e38f, -3.0e38f};
    const short8* wt = (const short8*)wtab;
    for (int g = 0; g < 4; ++g) {
        floatx4 acc = {0.f, 0.f, 0.f, 0.f};
        #pragma unroll
        for (int kw = 0; kw < 3; ++kw) {
            #pragma unroll
            for (int h = 0; h < 2; ++h) {
                const short8 af = wt[((g * 3 + kw) * 2 + h) * 64 + lane];
                const short8 bf = *(const short8*)baddr[kw][h];
                acc = __builtin_amdgcn_mfma_f32_16x16x32_bf16(af, bf, acc, 0, 0, 0);
            }
        }
        #pragma unroll
        for (int r = 0; r < 4; ++r) mx[r] = fmaxf(mx[r], acc[r]);  // pool d,h
    }

    // ---- epilogue (verified): ch = q*4+r; relu(max+conv_b); w-pair; reduce ----
    float vsum = 0.f;
    #pragma unroll
    for (int r = 0; r < 4; ++r) {
        const float cb = cbg[q * 4 + r];
        float v = fmaxf(mx[r] + cb, 0.f);
        float o = __shfl_xor(v, 1, 64);
        vsum += fmaxf(v, o);
    }
    const bool ok = ((lane & 1) == 0) && (w0 + (n & 14) <= 124);  // conv W = 126
    float s = ok ? vsum : 0.f;
    #pragma unroll
    for (int off = 1; off < 64; off <<= 1) s += __shfl_xor(s, off, 64);

    if (lane == 0) wsums[wv] = s;
    __syncthreads();
    if (tid == 0) {
        float bs = 0.f;
        #pragma unroll
        for (int i = 0; i < 8; ++i) bs += wsums[i];
        atomicAdd(&out[b], bs * (1.0f / 119070.0f));   // /(15*63*63)/2
    }
}

extern "C" void kernel_launch(void* const* d_in, const int* in_sizes, int n_in,
                              void* d_out, int out_size, void* d_ws, size_t ws_size,
                              hipStream_t stream) {
    const float* x      = (const float*)d_in[0];
    const float* conv_w = (const float*)d_in[1];
    const float* conv_b = (const float*)d_in[2];
    const float* bias   = (const float*)d_in[3];
    float* out = (float*)d_out;
    short* wtab = (short*)d_ws;   // 24,576 B

    init_kernel<<<1, 512, 0, stream>>>(conv_w, bias, wtab, out);
    dim3 grid(63, 15, 32);  // (hp, dp, b)
    fused_conv_pool_reduce<<<grid, 512, 0, stream>>>(x, wtab, conv_b, out);
}

// Round 9
// 330.796 us; speedup vs baseline: 1.8173x; 1.8173x over previous
//
#include <hip/hip_runtime.h>
#include <hip/hip_bf16.h>

// Fused Conv3d(3->16,k=3,valid) + conv_b + ReLU + maxpool2x2x2
// + spatial mean(fp32) + /2 + bias + channel-sum  ->  out[32] fp32.
// Inputs are FLOAT32 (harness materializes reference fp16 as f32).
//
// R9: persistent-ish blocks + 32x32x16 MFMA.
//  Block = (hp, b), loops dp=0..14 with register prefetch of next cell.
//  LDS rawT[row=w 0..129][tap = hl*16 + ci*4 + dl] bf16, 128 B/row, 16B
//  chunks XOR-swizzled by (row^(row>>3))&7. ci=3 pad + rows 128/129 zeroed.
//  MFMA m32n32k16: M=(dd,ch) rows, N=(hh,wi) cols, K=(ci,dl) per kh-chunk,
//  kw via row-shifted B; 9 MFMAs/wave/iter, ONE acc (kh,kw are conv sums).
//  Weights zero-padded per (kh,kw) in wtab (init kernel), resident in VGPRs.
//  D (m74/m101): col=lane&31, row=(reg&3)+8*(reg>>2)+4*(lane>>5).
//  Pool: dd = acc[r] vs acc[r+8] (in-reg), hh = shfl_xor 16, w = shfl_xor 1.
//  vsum accumulates across dp; one wave/block reduce + atomicAdd at end.

typedef __attribute__((ext_vector_type(8)))  short  short8;
typedef __attribute__((ext_vector_type(4)))  float  floatx4;
typedef __attribute__((ext_vector_type(16))) float  floatx16;

__device__ __forceinline__ short f2bf(float f) {
    unsigned u = __builtin_bit_cast(unsigned, f);
    unsigned r = (u + 0x7FFFu + ((u >> 16) & 1u)) >> 16;
    return (short)r;
}

__device__ __forceinline__ unsigned pkbf2(float a, float b) {
    __hip_bfloat162 h = __float22bfloat162_rn(float2{a, b});  // v_cvt_pk_bf16_f32
    unsigned r;
    __builtin_memcpy(&r, &h, 4);
    return r;
}

// ---- init: wtab[f=kh*3+kw][lane][8] zero-padded A-frags + out = bias sums ----
__global__ void init_kernel(const float* __restrict__ wg,
                            const float* __restrict__ biasg,
                            short* __restrict__ wtab,   // d_ws: 9*64*8 bf16 = 9216 B
                            float* __restrict__ out)    // [32]
{
    const int t = threadIdx.x;               // 0..575
    if (t < 576) {
        const int lane = t & 63, f = t >> 6;
        const int kh = f / 3, kw = f % 3;
        const int m = lane & 31, hs = lane >> 5;
        const int dd = m >> 4, ch = m & 15;
        short8 v;
        #pragma unroll
        for (int j = 0; j < 8; ++j) {
            const int s = hs * 8 + j;        // k-slot: ci = s>>2, dl = s&3
            const int ci = s >> 2, dl = s & 3;
            const int kd = dl - dd;
            v[j] = (ci < 3 && kd >= 0 && kd < 3)
                 ? f2bf(wg[ch * 81 + ci * 27 + kd * 9 + kh * 3 + kw]) : (short)0;
        }
        ((short8*)wtab)[f * 64 + lane] = v;
    }
    if (t < 32) {
        float s = 0.f;
        #pragma unroll
        for (int cc = 0; cc < 16; ++cc) s += biasg[cc];
        out[t] = s;   // conv blocks atomicAdd on top
    }
}

__global__ __launch_bounds__(512, 4) void fused_conv_pool_reduce(
    const float* __restrict__ xg,    // f32 [32][3][32][128][128]
    const short* __restrict__ wtab,  // bf16 frag table in d_ws
    const float* __restrict__ cbg,   // f32 [16]
    float* __restrict__ out)         // f32 [32]
{
    __shared__ __align__(16) short rawT[130 * 64];  // 16,640 B
    __shared__ float wsums[8];

    const int hp  = blockIdx.x;   // 0..62
    const int b   = blockIdx.y;   // 0..31
    const int tid = threadIdx.x;  // 0..511
    const int lane = tid & 63;
    const int wv   = tid >> 6;    // wave = 16-wide w tile
    const int hs   = lane >> 5;

    // ---- resident A-frags (36 VGPR) and conv-bias values ----
    short8 af[9];
    #pragma unroll
    for (int f = 0; f < 9; ++f) af[f] = ((const short8*)wtab)[f * 64 + lane];
    float cb8[8];
    #pragma unroll
    for (int r = 0; r < 8; ++r) cb8[r] = cbg[(r & 3) + 8 * (r >> 2) + 4 * hs];

    // ---- zero ci=3 pads (odd-chunk upper 8 B, rows 0..127) + rows 128/129 ----
    {
        const int row = tid >> 2, hl = tid & 3;
        const int phys = ((hl * 2 + 1) ^ ((row ^ (row >> 3)) & 7));
        *(unsigned long long*)((char*)rawT + row * 128 + phys * 16 + 8) = 0ULL;
    }
    if (tid < 32)
        *(unsigned long long*)((char*)rawT + 16384 + tid * 8) = 0ULL;

    // ---- dp-invariant addresses ----
    const int w4 = tid & 31, hr = (tid >> 5) & 3, dr = (tid >> 7) & 3;
    int waddr[3][4];
    #pragma unroll
    for (int ci = 0; ci < 3; ++ci) {
        #pragma unroll
        for (int i = 0; i < 4; ++i) {
            const int row = 4 * w4 + i;
            const int phys = (hr * 2 + (ci >> 1)) ^ ((row ^ (row >> 3)) & 7);
            waddr[ci][i] = row * 128 + phys * 16 + ((ci * 4 + dr) & 7) * 2;
        }
    }
    const int wi = lane & 15, hh = (lane >> 4) & 1;
    int raddr[3][3];
    #pragma unroll
    for (int kh = 0; kh < 3; ++kh) {
        #pragma unroll
        for (int kw = 0; kw < 3; ++kw) {
            const int row = wv * 16 + wi + kw;
            const int phys = ((hh + kh) * 2 + hs) ^ ((row ^ (row >> 3)) & 7);
            raddr[kh][kw] = row * 128 + phys * 16;
        }
    }

    // ---- prefetch dp=0 ----
    const float* src = xg + ((size_t)b * 96 + dr) * 16384 + (2 * hp + hr) * 128 + 4 * w4;
    floatx4 c0 = *(const floatx4*)(src);
    floatx4 c1 = *(const floatx4*)(src + 524288);
    floatx4 c2 = *(const floatx4*)(src + 1048576);

    float vsum = 0.f;
    for (int dp = 0; dp < 15; ++dp) {
        // stage current cell (4 b16 writes per ci)
        #pragma unroll
        for (int ci = 0; ci < 3; ++ci) {
            const floatx4 c = (ci == 0) ? c0 : (ci == 1) ? c1 : c2;
            const unsigned p0 = pkbf2(c[0], c[1]);
            const unsigned p1 = pkbf2(c[2], c[3]);
            *(short*)((char*)rawT + waddr[ci][0]) = (short)(p0 & 0xFFFF);
            *(short*)((char*)rawT + waddr[ci][1]) = (short)(p0 >> 16);
            *(short*)((char*)rawT + waddr[ci][2]) = (short)(p1 & 0xFFFF);
            *(short*)((char*)rawT + waddr[ci][3]) = (short)(p1 >> 16);
        }
        // prefetch next cell (overlaps MFMA + barriers)
        if (dp < 14) {
            src += 32768;
            c0 = *(const floatx4*)(src);
            c1 = *(const floatx4*)(src + 524288);
            c2 = *(const floatx4*)(src + 1048576);
        }
        __syncthreads();

        floatx16 acc = {0.f,0.f,0.f,0.f,0.f,0.f,0.f,0.f,
                        0.f,0.f,0.f,0.f,0.f,0.f,0.f,0.f};
        #pragma unroll
        for (int kh = 0; kh < 3; ++kh) {
            #pragma unroll
            for (int kw = 0; kw < 3; ++kw) {
                const short8 bf = *(const short8*)((char*)rawT + raddr[kh][kw]);
                acc = __builtin_amdgcn_mfma_f32_32x32x16_bf16(af[kh * 3 + kw], bf, acc, 0, 0, 0);
            }
        }
        // epilogue: dd-pool in-reg, +conv_b, relu, hh-pool, w-pair pool, sum ch
        #pragma unroll
        for (int r = 0; r < 8; ++r) {
            float v = fmaxf(fmaxf(acc[r], acc[r + 8]) + cb8[r], 0.f);
            v = fmaxf(v, __shfl_xor(v, 16, 64));   // pool over hh
            v = fmaxf(v, __shfl_xor(v, 1, 64));    // pool over w pair
            vsum += v;
        }
        __syncthreads();   // WAR guard before next stage
    }

    // valid lanes: wi even, hh==0 side, pooled pair base <= 124 (conv W = 126)
    const bool okl = ((lane & 0x11) == 0) && (wv * 16 + (lane & 14) <= 124);
    float s = okl ? vsum : 0.f;
    #pragma unroll
    for (int off = 1; off < 64; off <<= 1) s += __shfl_xor(s, off, 64);

    if (lane == 0) wsums[wv] = s;
    __syncthreads();
    if (tid == 0) {
        float bs = 0.f;
        #pragma unroll
        for (int i = 0; i < 8; ++i) bs += wsums[i];
        atomicAdd(&out[b], bs * (1.0f / 119070.0f));   // /(15*63*63)/2
    }
}

extern "C" void kernel_launch(void* const* d_in, const int* in_sizes, int n_in,
                              void* d_out, int out_size, void* d_ws, size_t ws_size,
                              hipStream_t stream) {
    const float* x      = (const float*)d_in[0];
    const float* conv_w = (const float*)d_in[1];
    const float* conv_b = (const float*)d_in[2];
    const float* bias   = (const float*)d_in[3];
    float* out = (float*)d_out;
    short* wtab = (short*)d_ws;   // 9216 B

    init_kernel<<<1, 576, 0, stream>>>(conv_w, bias, wtab, out);
    dim3 grid(63, 32);  // (hp, b)
    fused_conv_pool_reduce<<<grid, 512, 0, stream>>>(x, wtab, conv_b, out);
}